// Round 1
// baseline (588.290 us; speedup 1.0000x reference)
//
#include <hip/hip_runtime.h>

// Linformer head, fp32 baseline.
// B=16, S=4096, D=64, KP=256.
// d_in: Q[B,S,D], K[B,S,D], V[B,S,D], E_w[KP,S], E_b[KP], F_w[KP,S], F_b[KP]
// d_out: out[B,S,D] ++ attn[B,S,KP]
// d_ws: KpT[B,KP,D] ++ Vp[B,KP,D]  (2 MB)

#define B_  16
#define S_  4096
#define D_  64
#define KP_ 256

// ---------------------------------------------------------------------------
// Kernel 1: projections.
//   KpT[b][k][d] = sum_s E_w[k][s] * K[b][s][d] + E_b[k]
//   Vp [b][k][d] = sum_s F_w[k][s] * V[b][s][d] + F_b[k]
// grid (8, 2, 16): x = 32-wide k tile, y = which projection, z = batch.
// Each wave owns 8 k-rows (d = lane). W rows fetched through wave-uniform
// pointers (readfirstlane) so they compile to s_load; src chunk staged in LDS
// with a register prefetch pipeline to hide global latency at 1 block/CU.
// ---------------------------------------------------------------------------
__global__ __launch_bounds__(256, 2)
void proj_kernel(const float* __restrict__ Kg, const float* __restrict__ Vg,
                 const float* __restrict__ E_w, const float* __restrict__ E_b,
                 const float* __restrict__ F_w, const float* __restrict__ F_b,
                 float* __restrict__ KpT, float* __restrict__ Vp)
{
    const int kt   = blockIdx.x;   // 0..7
    const int proj = blockIdx.y;   // 0 -> Kp, 1 -> Vp
    const int b    = blockIdx.z;

    const float* src  = (proj == 0 ? Kg : Vg) + (size_t)b * S_ * D_;
    const float* W    = (proj == 0 ? E_w : F_w);
    const float* bias = (proj == 0 ? E_b : F_b);
    float* outp = (proj == 0 ? KpT : Vp) + (size_t)b * KP_ * D_;

    const int t    = threadIdx.x;
    const int lane = t & 63;
    const int wave = t >> 6;

    __shared__ __align__(16) float bs[64 * 64];   // [s-chunk 64][d 64], 16 KB

    const int k0 = kt * 32 + wave * 8;
    const float* Wrow[8];
#pragma unroll
    for (int j = 0; j < 8; ++j) {
        int kj = __builtin_amdgcn_readfirstlane(k0 + j);  // force SGPR -> s_load path
        Wrow[j] = W + (size_t)kj * S_;
    }

    float acc[8] = {0.f,0.f,0.f,0.f,0.f,0.f,0.f,0.f};

    // prefetch chunk 0 into registers
    float4 pre[4];
    {
        const float4* g = (const float4*)src;
#pragma unroll
        for (int i = 0; i < 4; ++i) pre[i] = g[i * 256 + t];
    }

    for (int ch = 0; ch < S_ / 64; ++ch) {
        __syncthreads();
#pragma unroll
        for (int i = 0; i < 4; ++i) ((float4*)bs)[i * 256 + t] = pre[i];
        __syncthreads();
        if (ch + 1 < S_ / 64) {   // issue next chunk's loads; waited on next iter
            const float4* g = (const float4*)(src + (size_t)(ch + 1) * 64 * D_);
#pragma unroll
            for (int i = 0; i < 4; ++i) pre[i] = g[i * 256 + t];
        }
        const int s0 = ch * 64;
#pragma unroll 2
        for (int s4 = 0; s4 < 16; ++s4) {
            float4 w4[8];
#pragma unroll
            for (int j = 0; j < 8; ++j)
                w4[j] = *(const float4*)(Wrow[j] + s0 + s4 * 4);   // uniform -> s_load_dwordx4
#pragma unroll
            for (int c = 0; c < 4; ++c) {
                float bval = bs[(s4 * 4 + c) * 64 + lane];   // bank = lane%32, 2-way = free
#pragma unroll
                for (int j = 0; j < 8; ++j)
                    acc[j] = fmaf(bval, ((const float*)&w4[j])[c], acc[j]);
            }
        }
    }
#pragma unroll
    for (int j = 0; j < 8; ++j)
        outp[(size_t)(k0 + j) * D_ + lane] = acc[j] + bias[k0 + j];
}

// ---------------------------------------------------------------------------
// Kernel 2: fused scores -> softmax -> attn write -> out = attn @ Vp.
// grid (S/32, B); block 256 = 4 waves; 32 s-rows per block.
// Phase 1: thread owns 4 s-rows x 8 k (two k-quads, {4*kg} and {128+4*kg});
//   KpT staged transposed [d][k] (pitch 132, two 128-k halves) so k-quad
//   ds_read_b128 is lane-consecutive = conflict-free. VALU-bound (128 FMA vs
//   96 LDS cycles per d4 step).
// Softmax: per-row max/sum via __shfl_xor over 32-lane halves.
// Phase 3: attn round-trips through LDS (pitch 260); Vp streamed in 4 chunks
//   of 64 rows. Thread owns 2 s x 4 d outputs.
// Total LDS 58368 B -> 2 blocks/CU.
// ---------------------------------------------------------------------------
__global__ __launch_bounds__(256, 2)
void attn_kernel(const float* __restrict__ Qg, const float* __restrict__ KpT,
                 const float* __restrict__ Vp, float* __restrict__ attn_out,
                 float* __restrict__ outg)
{
    const int st = blockIdx.x;
    const int b  = blockIdx.y;
    const int t  = threadIdx.x;

    __shared__ __align__(16) float smem[14592];
    float* kp_lds = smem;            // phase1: [d 64][k 128] pitch 132 (8448 f)
    float* q_lds  = smem + 8448;     // [s 32][d 64] (2048 f)
    float* at_lds = smem;            // phase3: [s 32][k 256] pitch 260 (8320 f), overlays kp
    float* vp_lds = smem + 10496;    // phase3: [kk 64][d 64] (4096 f)

    // stage Q tile (flat copy, coalesced)
    {
        const float4* qg4 = (const float4*)(Qg + ((size_t)b * S_ + (size_t)st * 32) * D_);
#pragma unroll
        for (int i = 0; i < 2; ++i) {
            int f = i * 256 + t;
            ((float4*)q_lds)[f] = qg4[f];
        }
    }

    const int kg = t & 31;     // k-quad id: k = 4*kg (+128 for half 1)
    const int sg = t >> 5;     // 0..7
    const int s0 = sg * 4;

    float acc[4][8];
#pragma unroll
    for (int si = 0; si < 4; ++si)
#pragma unroll
        for (int j = 0; j < 8; ++j) acc[si][j] = 0.f;

    const float4* kpg = (const float4*)(KpT + (size_t)b * KP_ * D_);

    for (int half = 0; half < 2; ++half) {
        __syncthreads();
        // stage 128 KpT rows transposed into kp_lds[d][k]
#pragma unroll
        for (int i = 0; i < 8; ++i) {
            int f  = i * 256 + t;   // 2048 float4 this half
            int k  = f >> 4;        // 0..127
            int d4 = f & 15;
            float4 v = kpg[(size_t)(half * 128 + k) * 16 + d4];
            kp_lds[(d4 * 4 + 0) * 132 + k] = v.x;
            kp_lds[(d4 * 4 + 1) * 132 + k] = v.y;
            kp_lds[(d4 * 4 + 2) * 132 + k] = v.z;
            kp_lds[(d4 * 4 + 3) * 132 + k] = v.w;
        }
        __syncthreads();
#pragma unroll 2
        for (int d4 = 0; d4 < 16; ++d4) {
            float4 qv[4];
#pragma unroll
            for (int si = 0; si < 4; ++si)
                qv[si] = *(const float4*)&q_lds[(s0 + si) * 64 + d4 * 4];  // broadcast
#pragma unroll
            for (int dd = 0; dd < 4; ++dd) {
                float4 kv = *(const float4*)&kp_lds[(d4 * 4 + dd) * 132 + kg * 4];
#pragma unroll
                for (int si = 0; si < 4; ++si) {
                    float qs = ((const float*)&qv[si])[dd];
                    acc[si][half*4+0] = fmaf(qs, kv.x, acc[si][half*4+0]);
                    acc[si][half*4+1] = fmaf(qs, kv.y, acc[si][half*4+1]);
                    acc[si][half*4+2] = fmaf(qs, kv.z, acc[si][half*4+2]);
                    acc[si][half*4+3] = fmaf(qs, kv.w, acc[si][half*4+3]);
                }
            }
        }
    }

    // softmax over 256 k: 8 per thread x 32 lanes per row-group
    const float scale = 0.125f;   // 1/sqrt(64)
    float p[4][8];
#pragma unroll
    for (int si = 0; si < 4; ++si) {
        float m = -3.4e38f;
#pragma unroll
        for (int j = 0; j < 8; ++j) {
            p[si][j] = acc[si][j] * scale;
            m = fmaxf(m, p[si][j]);
        }
#pragma unroll
        for (int off = 16; off > 0; off >>= 1)
            m = fmaxf(m, __shfl_xor(m, off, 32));
        float sum = 0.f;
#pragma unroll
        for (int j = 0; j < 8; ++j) {
            p[si][j] = __expf(p[si][j] - m);
            sum += p[si][j];
        }
#pragma unroll
        for (int off = 16; off > 0; off >>= 1)
            sum += __shfl_xor(sum, off, 32);
        float inv = 1.f / sum;
#pragma unroll
        for (int j = 0; j < 8; ++j) p[si][j] *= inv;
    }

    __syncthreads();   // everyone done reading kp_lds / q_lds

    // write attn to global (coalesced float4) and into LDS for phase 3
    float* attn_b = attn_out + ((size_t)b * S_ + (size_t)st * 32) * KP_;
#pragma unroll
    for (int si = 0; si < 4; ++si) {
        int srow = s0 + si;
        float4 pa = make_float4(p[si][0], p[si][1], p[si][2], p[si][3]);
        float4 pb = make_float4(p[si][4], p[si][5], p[si][6], p[si][7]);
        *(float4*)&attn_b[(size_t)srow * KP_ + kg * 4]       = pa;
        *(float4*)&attn_b[(size_t)srow * KP_ + 128 + kg * 4] = pb;
        *(float4*)&at_lds[srow * 260 + kg * 4]       = pa;
        *(float4*)&at_lds[srow * 260 + 128 + kg * 4] = pb;
    }

    // phase 3: out[s][d] = sum_k attn[s][k] * Vp[k][d]; thread owns 2 s x 4 d
    const int dg  = t & 15;
    const int d0  = dg * 4;
    const int sg3 = t >> 4;        // 0..15
    const int sA  = sg3 * 2, sB = sA + 1;
    float accA[4] = {0,0,0,0}, accB[4] = {0,0,0,0};

    const float4* vg4 = (const float4*)(Vp + (size_t)b * KP_ * D_);
    for (int kc = 0; kc < 4; ++kc) {
        __syncthreads();   // kc=0: attn LDS writes visible; else: prev chunk reads done
#pragma unroll
        for (int i = 0; i < 4; ++i) {
            int f = i * 256 + t;
            ((float4*)vp_lds)[f] = vg4[kc * 1024 + f];
        }
        __syncthreads();
#pragma unroll 4
        for (int kk = 0; kk < 64; ++kk) {
            int k = kc * 64 + kk;
            float4 v4 = *(const float4*)&vp_lds[kk * 64 + d0];
            float a0 = at_lds[sA * 260 + k];
            float a1 = at_lds[sB * 260 + k];
            accA[0] = fmaf(a0, v4.x, accA[0]);
            accA[1] = fmaf(a0, v4.y, accA[1]);
            accA[2] = fmaf(a0, v4.z, accA[2]);
            accA[3] = fmaf(a0, v4.w, accA[3]);
            accB[0] = fmaf(a1, v4.x, accB[0]);
            accB[1] = fmaf(a1, v4.y, accB[1]);
            accB[2] = fmaf(a1, v4.z, accB[2]);
            accB[3] = fmaf(a1, v4.w, accB[3]);
        }
    }

    float* out_b = outg + ((size_t)b * S_ + (size_t)st * 32) * D_;
    *(float4*)&out_b[(size_t)sA * D_ + d0] = make_float4(accA[0], accA[1], accA[2], accA[3]);
    *(float4*)&out_b[(size_t)sB * D_ + d0] = make_float4(accB[0], accB[1], accB[2], accB[3]);
}

extern "C" void kernel_launch(void* const* d_in, const int* in_sizes, int n_in,
                              void* d_out, int out_size, void* d_ws, size_t ws_size,
                              hipStream_t stream) {
    const float* Q   = (const float*)d_in[0];
    const float* K   = (const float*)d_in[1];
    const float* V   = (const float*)d_in[2];
    const float* E_w = (const float*)d_in[3];
    const float* E_b = (const float*)d_in[4];
    const float* F_w = (const float*)d_in[5];
    const float* F_b = (const float*)d_in[6];

    float* out  = (float*)d_out;                       // [B,S,D]
    float* attn = out + (size_t)B_ * S_ * D_;          // [B,S,KP]

    float* KpT = (float*)d_ws;                         // [B,KP,D]
    float* Vp  = KpT + (size_t)B_ * KP_ * D_;          // [B,KP,D]

    proj_kernel<<<dim3(KP_ / 32, 2, B_), 256, 0, stream>>>(K, V, E_w, E_b, F_w, F_b, KpT, Vp);
    attn_kernel<<<dim3(S_ / 32, B_), 256, 0, stream>>>(Q, KpT, Vp, attn, out);
}

// Round 2
// 417.888 us; speedup vs baseline: 1.4078x; 1.4078x over previous
//
#include <hip/hip_runtime.h>

// Linformer head, fp32. B=16, S=4096, D=64, KP=256.
// d_in: Q[B,S,D], K[B,S,D], V[B,S,D], E_w[KP,S], E_b[KP], F_w[KP,S], F_b[KP]
// d_out: out[B,S,D] ++ attn[B,S,KP]
// d_ws: KpT[B,KP,D] ++ Vp[B,KP,D]  (2 MB)
//
// R2: proj split-S (8 chunks) + atomicAdd into bias-initialized ws -> 2048
// blocks (8/CU, 100% occ) vs R1's 256 blocks (12% occ, VALUBusy 8%).
// attn: LDS 58.4->48.5 KB (3 blocks/CU), kp staging pitch 132->129 (8-way
// bank conflict -> 2-way free).

#define B_  16
#define S_  4096
#define D_  64
#define KP_ 256

// ---------------------------------------------------------------------------
// Kernel 0: write bias into the projection accumulators (ws is poisoned 0xAA
// before every timed call, so this runs every launch).
// ---------------------------------------------------------------------------
__global__ __launch_bounds__(256)
void init_bias_kernel(const float* __restrict__ E_b, const float* __restrict__ F_b,
                      float* __restrict__ KpT, float* __restrict__ Vp)
{
    int i = blockIdx.x * 256 + threadIdx.x;   // over B_*KP_*D_ = 262144
    int k = (i >> 6) & (KP_ - 1);
    KpT[i] = E_b[k];
    Vp[i]  = F_b[k];
}

// ---------------------------------------------------------------------------
// Kernel 1: projections, split-S with atomic reduction.
//   KpT[b][k][d] += sum_{s in chunk} E_w[k][s] * K[b][s][d]   (bias pre-added)
//   Vp [b][k][d] += sum_{s in chunk} F_w[k][s] * V[b][s][d]
// grid (8, 2, 128): x = 32-wide k tile, y = projection, z = b*8 + s-chunk.
// 2048 blocks x 4 waves, 16 KB LDS -> 8 blocks/CU = 32 waves/CU.
// Wave owns 8 k-rows (d = lane); W rows via wave-uniform s_load_dwordx4.
// ---------------------------------------------------------------------------
__global__ __launch_bounds__(256, 8)
void proj_kernel(const float* __restrict__ Kg, const float* __restrict__ Vg,
                 const float* __restrict__ E_w, const float* __restrict__ F_w,
                 float* __restrict__ KpT, float* __restrict__ Vp)
{
    const int kt   = blockIdx.x;       // 0..7
    const int proj = blockIdx.y;       // 0 -> Kp, 1 -> Vp
    const int b    = blockIdx.z >> 3;  // 0..15
    const int sc   = blockIdx.z & 7;   // 0..7 : s-chunk of 512

    const float* src = (proj == 0 ? Kg : Vg) + ((size_t)b * S_ + (size_t)sc * 512) * D_;
    const float* W   = (proj == 0 ? E_w : F_w);
    float* outp = (proj == 0 ? KpT : Vp) + (size_t)b * KP_ * D_;

    const int t    = threadIdx.x;
    const int lane = t & 63;
    const int wave = t >> 6;

    __shared__ __align__(16) float bs[64 * 64];   // [s 64][d 64], 16 KB

    const int k0 = kt * 32 + wave * 8;
    const int sbase = sc * 512;
    const float* Wrow[8];
#pragma unroll
    for (int j = 0; j < 8; ++j) {
        int kj = __builtin_amdgcn_readfirstlane(k0 + j);  // SGPR -> s_load path
        Wrow[j] = W + (size_t)kj * S_ + sbase;
    }

    float acc[8] = {0.f,0.f,0.f,0.f,0.f,0.f,0.f,0.f};

    float4 pre[4];
    {
        const float4* g = (const float4*)src;
#pragma unroll
        for (int i = 0; i < 4; ++i) pre[i] = g[i * 256 + t];
    }

    for (int ch = 0; ch < 8; ++ch) {              // 8 chunks of 64 s
        __syncthreads();
#pragma unroll
        for (int i = 0; i < 4; ++i) ((float4*)bs)[i * 256 + t] = pre[i];
        __syncthreads();
        if (ch + 1 < 8) {
            const float4* g = (const float4*)(src + (size_t)(ch + 1) * 64 * D_);
#pragma unroll
            for (int i = 0; i < 4; ++i) pre[i] = g[i * 256 + t];
        }
        const int s0 = ch * 64;
#pragma unroll 2
        for (int s4 = 0; s4 < 16; ++s4) {
            float4 w4[8];
#pragma unroll
            for (int j = 0; j < 8; ++j)
                w4[j] = *(const float4*)(Wrow[j] + s0 + s4 * 4);   // s_load_dwordx4
#pragma unroll
            for (int c = 0; c < 4; ++c) {
                float bval = bs[(s4 * 4 + c) * 64 + lane];
#pragma unroll
                for (int j = 0; j < 8; ++j)
                    acc[j] = fmaf(bval, ((const float*)&w4[j])[c], acc[j]);
            }
        }
    }
#pragma unroll
    for (int j = 0; j < 8; ++j)
        atomicAdd(&outp[(size_t)(k0 + j) * D_ + lane], acc[j]);
}

// ---------------------------------------------------------------------------
// Kernel 2: fused scores -> softmax -> attn write -> out = attn @ Vp.
// grid (S/32, B); block 256 = 4 waves; 32 s-rows per block.
// LDS 48.5 KB, __launch_bounds__(256,3) -> 3 blocks/CU.
// kp staging pitch 129: transpose-scatter banks = (4*d4 + c + k) % 32 ->
// 2-way (free) instead of pitch-132's 8-way.
// ---------------------------------------------------------------------------
__global__ __launch_bounds__(256, 3)
void attn_kernel(const float* __restrict__ Qg, const float* __restrict__ KpT,
                 const float* __restrict__ Vp, float* __restrict__ attn_out,
                 float* __restrict__ outg)
{
    const int st = blockIdx.x;
    const int b  = blockIdx.y;
    const int t  = threadIdx.x;

    __shared__ __align__(16) float smem[12416];
    float* kp_lds = smem;            // phase1: [d 64][k 128] pitch 129 (8256 f)
    float* q_lds  = smem + 8320;     // [s 32][d 64] (2048 f)
    float* at_lds = smem;            // phase3: [s 32][k 256] pitch 260 (8320 f)
    float* vp_lds = smem + 8320;     // phase3: [kk 64][d 64] (4096 f), overlays dead q

    {
        const float4* qg4 = (const float4*)(Qg + ((size_t)b * S_ + (size_t)st * 32) * D_);
#pragma unroll
        for (int i = 0; i < 2; ++i) {
            int f = i * 256 + t;
            ((float4*)q_lds)[f] = qg4[f];
        }
    }

    const int kg = t & 31;     // k-quad id: k = 4*kg (+128 for half 1)
    const int sg = t >> 5;     // 0..7
    const int s0 = sg * 4;

    float acc[4][8];
#pragma unroll
    for (int si = 0; si < 4; ++si)
#pragma unroll
        for (int j = 0; j < 8; ++j) acc[si][j] = 0.f;

    const float4* kpg = (const float4*)(KpT + (size_t)b * KP_ * D_);

    for (int half = 0; half < 2; ++half) {
        __syncthreads();
#pragma unroll
        for (int i = 0; i < 8; ++i) {
            int f  = i * 256 + t;   // 2048 float4 this half
            int k  = f >> 4;        // 0..127
            int d4 = f & 15;
            float4 v = kpg[(size_t)(half * 128 + k) * 16 + d4];
            kp_lds[(d4 * 4 + 0) * 129 + k] = v.x;
            kp_lds[(d4 * 4 + 1) * 129 + k] = v.y;
            kp_lds[(d4 * 4 + 2) * 129 + k] = v.z;
            kp_lds[(d4 * 4 + 3) * 129 + k] = v.w;
        }
        __syncthreads();
#pragma unroll 2
        for (int d4 = 0; d4 < 16; ++d4) {
            float4 qv[4];
#pragma unroll
            for (int si = 0; si < 4; ++si)
                qv[si] = *(const float4*)&q_lds[(s0 + si) * 64 + d4 * 4];
#pragma unroll
            for (int dd = 0; dd < 4; ++dd) {
                float4 kv = *(const float4*)&kp_lds[(d4 * 4 + dd) * 129 + kg * 4];
#pragma unroll
                for (int si = 0; si < 4; ++si) {
                    float qs = ((const float*)&qv[si])[dd];
                    acc[si][half*4+0] = fmaf(qs, kv.x, acc[si][half*4+0]);
                    acc[si][half*4+1] = fmaf(qs, kv.y, acc[si][half*4+1]);
                    acc[si][half*4+2] = fmaf(qs, kv.z, acc[si][half*4+2]);
                    acc[si][half*4+3] = fmaf(qs, kv.w, acc[si][half*4+3]);
                }
            }
        }
    }

    // softmax over 256 k
    const float scale = 0.125f;   // 1/sqrt(64)
    float p[4][8];
#pragma unroll
    for (int si = 0; si < 4; ++si) {
        float m = -3.4e38f;
#pragma unroll
        for (int j = 0; j < 8; ++j) {
            p[si][j] = acc[si][j] * scale;
            m = fmaxf(m, p[si][j]);
        }
#pragma unroll
        for (int off = 16; off > 0; off >>= 1)
            m = fmaxf(m, __shfl_xor(m, off, 32));
        float sum = 0.f;
#pragma unroll
        for (int j = 0; j < 8; ++j) {
            p[si][j] = __expf(p[si][j] - m);
            sum += p[si][j];
        }
#pragma unroll
        for (int off = 16; off > 0; off >>= 1)
            sum += __shfl_xor(sum, off, 32);
        float inv = 1.f / sum;
#pragma unroll
        for (int j = 0; j < 8; ++j) p[si][j] *= inv;
    }

    __syncthreads();   // phase-1 reads of kp_lds / q_lds all done

    float* attn_b = attn_out + ((size_t)b * S_ + (size_t)st * 32) * KP_;
#pragma unroll
    for (int si = 0; si < 4; ++si) {
        int srow = s0 + si;
        float4 pa = make_float4(p[si][0], p[si][1], p[si][2], p[si][3]);
        float4 pb = make_float4(p[si][4], p[si][5], p[si][6], p[si][7]);
        *(float4*)&attn_b[(size_t)srow * KP_ + kg * 4]       = pa;
        *(float4*)&attn_b[(size_t)srow * KP_ + 128 + kg * 4] = pb;
        *(float4*)&at_lds[srow * 260 + kg * 4]       = pa;
        *(float4*)&at_lds[srow * 260 + 128 + kg * 4] = pb;
    }

    // phase 3: out[s][d] = sum_k attn[s][k] * Vp[k][d]; thread owns 2 s x 4 d
    const int dg  = t & 15;
    const int d0  = dg * 4;
    const int sg3 = t >> 4;        // 0..15
    const int sA  = sg3 * 2, sB = sA + 1;
    float accA[4] = {0,0,0,0}, accB[4] = {0,0,0,0};

    const float4* vg4 = (const float4*)(Vp + (size_t)b * KP_ * D_);
    for (int kc = 0; kc < 4; ++kc) {
        __syncthreads();   // kc=0: at_lds writes visible (and q dead); else prev reads done
#pragma unroll
        for (int i = 0; i < 4; ++i) {
            int f = i * 256 + t;
            ((float4*)vp_lds)[f] = vg4[kc * 1024 + f];
        }
        __syncthreads();
#pragma unroll 4
        for (int kk = 0; kk < 64; ++kk) {
            int k = kc * 64 + kk;
            float4 v4 = *(const float4*)&vp_lds[kk * 64 + d0];
            float a0 = at_lds[sA * 260 + k];
            float a1 = at_lds[sB * 260 + k];
            accA[0] = fmaf(a0, v4.x, accA[0]);
            accA[1] = fmaf(a0, v4.y, accA[1]);
            accA[2] = fmaf(a0, v4.z, accA[2]);
            accA[3] = fmaf(a0, v4.w, accA[3]);
            accB[0] = fmaf(a1, v4.x, accB[0]);
            accB[1] = fmaf(a1, v4.y, accB[1]);
            accB[2] = fmaf(a1, v4.z, accB[2]);
            accB[3] = fmaf(a1, v4.w, accB[3]);
        }
    }

    float* out_b = outg + ((size_t)b * S_ + (size_t)st * 32) * D_;
    *(float4*)&out_b[(size_t)sA * D_ + d0] = make_float4(accA[0], accA[1], accA[2], accA[3]);
    *(float4*)&out_b[(size_t)sB * D_ + d0] = make_float4(accB[0], accB[1], accB[2], accB[3]);
}

extern "C" void kernel_launch(void* const* d_in, const int* in_sizes, int n_in,
                              void* d_out, int out_size, void* d_ws, size_t ws_size,
                              hipStream_t stream) {
    const float* Q   = (const float*)d_in[0];
    const float* K   = (const float*)d_in[1];
    const float* V   = (const float*)d_in[2];
    const float* E_w = (const float*)d_in[3];
    const float* E_b = (const float*)d_in[4];
    const float* F_w = (const float*)d_in[5];
    const float* F_b = (const float*)d_in[6];

    float* out  = (float*)d_out;                       // [B,S,D]
    float* attn = out + (size_t)B_ * S_ * D_;          // [B,S,KP]

    float* KpT = (float*)d_ws;                         // [B,KP,D]
    float* Vp  = KpT + (size_t)B_ * KP_ * D_;          // [B,KP,D]

    init_bias_kernel<<<dim3(B_ * KP_ * D_ / 256), 256, 0, stream>>>(E_b, F_b, KpT, Vp);
    proj_kernel<<<dim3(KP_ / 32, 2, B_ * 8), 256, 0, stream>>>(K, V, E_w, F_w, KpT, Vp);
    attn_kernel<<<dim3(S_ / 32, B_), 256, 0, stream>>>(Q, KpT, Vp, attn, out);
}

// Round 3
// 417.393 us; speedup vs baseline: 1.4094x; 1.0012x over previous
//
#include <hip/hip_runtime.h>

// Linformer head, fp32. B=16, S=4096, D=64, KP=256.
// d_in: Q[B,S,D], K[B,S,D], V[B,S,D], E_w[KP,S], E_b[KP], F_w[KP,S], F_b[KP]
// d_out: out[B,S,D] ++ attn[B,S,KP]
//
// R3: proj split-S now writes per-chunk PARTIAL buffers (plain coalesced
// stores) + reduce kernel, replacing R2's 4.2M device-scope atomicAdds that
// cost 540 MB of HBM RMW traffic (FETCH 259 + WRITE 267 MB, 64B line per
// 4B atomic). Needs 18.9 MB ws; falls back to the atomic path if ws is
// smaller (launch-time branch, deterministic -> graph-safe).
// attn kernel unchanged from R2 to isolate the change.

#define B_  16
#define S_  4096
#define D_  64
#define KP_ 256

#define NELEM   (B_ * KP_ * D_)       // 262144 elems = 1 MB per buffer
#define NSC     8                     // s-chunks of 512

// ---------------------------------------------------------------------------
// proj partials: P[(proj*NSC+sc)][b][k][d] = sum_{s in chunk} W[k][s]*src[s][d]
// grid (8, 2, 128): x = 32-wide k tile, y = projection, z = b*8 + sc.
// 2048 blocks x 4 waves, 16 KB LDS -> 8 blocks/CU.
// ---------------------------------------------------------------------------
__global__ __launch_bounds__(256, 8)
void proj_partial_kernel(const float* __restrict__ Kg, const float* __restrict__ Vg,
                         const float* __restrict__ E_w, const float* __restrict__ F_w,
                         float* __restrict__ Ppart)
{
    const int kt   = blockIdx.x;       // 0..7
    const int proj = blockIdx.y;       // 0 -> Kp, 1 -> Vp
    const int b    = blockIdx.z >> 3;  // 0..15
    const int sc   = blockIdx.z & 7;   // 0..7

    const float* src = (proj == 0 ? Kg : Vg) + ((size_t)b * S_ + (size_t)sc * 512) * D_;
    const float* W   = (proj == 0 ? E_w : F_w);
    float* outp = Ppart + ((size_t)(proj * NSC + sc) * B_ + b) * KP_ * D_;

    const int t    = threadIdx.x;
    const int lane = t & 63;
    const int wave = t >> 6;

    __shared__ __align__(16) float bs[64 * 64];   // [s 64][d 64], 16 KB

    const int k0 = kt * 32 + wave * 8;
    const int sbase = sc * 512;
    const float* Wrow[8];
#pragma unroll
    for (int j = 0; j < 8; ++j) {
        int kj = __builtin_amdgcn_readfirstlane(k0 + j);  // SGPR -> s_load path
        Wrow[j] = W + (size_t)kj * S_ + sbase;
    }

    float acc[8] = {0.f,0.f,0.f,0.f,0.f,0.f,0.f,0.f};

    float4 pre[4];
    {
        const float4* g = (const float4*)src;
#pragma unroll
        for (int i = 0; i < 4; ++i) pre[i] = g[i * 256 + t];
    }

    for (int ch = 0; ch < 8; ++ch) {              // 8 chunks of 64 s
        __syncthreads();
#pragma unroll
        for (int i = 0; i < 4; ++i) ((float4*)bs)[i * 256 + t] = pre[i];
        __syncthreads();
        if (ch + 1 < 8) {
            const float4* g = (const float4*)(src + (size_t)(ch + 1) * 64 * D_);
#pragma unroll
            for (int i = 0; i < 4; ++i) pre[i] = g[i * 256 + t];
        }
        const int s0 = ch * 64;
#pragma unroll 2
        for (int s4 = 0; s4 < 16; ++s4) {
            float4 w4[8];
#pragma unroll
            for (int j = 0; j < 8; ++j)
                w4[j] = *(const float4*)(Wrow[j] + s0 + s4 * 4);   // s_load_dwordx4
#pragma unroll
            for (int c = 0; c < 4; ++c) {
                float bval = bs[(s4 * 4 + c) * 64 + lane];
#pragma unroll
                for (int j = 0; j < 8; ++j)
                    acc[j] = fmaf(bval, ((const float*)&w4[j])[c], acc[j]);
            }
        }
    }
#pragma unroll
    for (int j = 0; j < 8; ++j)
        outp[(size_t)(k0 + j) * D_ + lane] = acc[j];   // plain coalesced store
}

// ---------------------------------------------------------------------------
// reduce: KpT = sum_sc P[0][sc] + E_b;  Vp = sum_sc P[1][sc] + F_b.
// grid 256 x 256; thread owns one float4 per proj. ~19 MB traffic, ~5 us.
// ---------------------------------------------------------------------------
__global__ __launch_bounds__(256)
void reduce_kernel(const float4* __restrict__ Ppart,
                   const float* __restrict__ E_b, const float* __restrict__ F_b,
                   float4* __restrict__ KpT, float4* __restrict__ Vp)
{
    const int i = blockIdx.x * 256 + threadIdx.x;   // 0..65535 (float4 idx)
    const int k = (i >> 4) & (KP_ - 1);             // 16 float4 per k-row

    float4 a = Ppart[i];
#pragma unroll
    for (int sc = 1; sc < NSC; ++sc) {
        float4 v = Ppart[(size_t)sc * (NELEM / 4) + i];
        a.x += v.x; a.y += v.y; a.z += v.z; a.w += v.w;
    }
    float be = E_b[k];
    a.x += be; a.y += be; a.z += be; a.w += be;
    KpT[i] = a;

    float4 c = Ppart[(size_t)NSC * (NELEM / 4) + i];
#pragma unroll
    for (int sc = 1; sc < NSC; ++sc) {
        float4 v = Ppart[(size_t)(NSC + sc) * (NELEM / 4) + i];
        c.x += v.x; c.y += v.y; c.z += v.z; c.w += v.w;
    }
    float bf = F_b[k];
    c.x += bf; c.y += bf; c.z += bf; c.w += bf;
    Vp[i] = c;
}

// --------------------- fallback (ws too small): R2 path ---------------------
__global__ __launch_bounds__(256)
void init_bias_kernel(const float* __restrict__ E_b, const float* __restrict__ F_b,
                      float* __restrict__ KpT, float* __restrict__ Vp)
{
    int i = blockIdx.x * 256 + threadIdx.x;
    int k = (i >> 6) & (KP_ - 1);
    KpT[i] = E_b[k];
    Vp[i]  = F_b[k];
}

__global__ __launch_bounds__(256, 8)
void proj_atomic_kernel(const float* __restrict__ Kg, const float* __restrict__ Vg,
                        const float* __restrict__ E_w, const float* __restrict__ F_w,
                        float* __restrict__ KpT, float* __restrict__ Vp)
{
    const int kt   = blockIdx.x;
    const int proj = blockIdx.y;
    const int b    = blockIdx.z >> 3;
    const int sc   = blockIdx.z & 7;

    const float* src = (proj == 0 ? Kg : Vg) + ((size_t)b * S_ + (size_t)sc * 512) * D_;
    const float* W   = (proj == 0 ? E_w : F_w);
    float* outp = (proj == 0 ? KpT : Vp) + (size_t)b * KP_ * D_;

    const int t    = threadIdx.x;
    const int lane = t & 63;
    const int wave = t >> 6;

    __shared__ __align__(16) float bs[64 * 64];

    const int k0 = kt * 32 + wave * 8;
    const int sbase = sc * 512;
    const float* Wrow[8];
#pragma unroll
    for (int j = 0; j < 8; ++j) {
        int kj = __builtin_amdgcn_readfirstlane(k0 + j);
        Wrow[j] = W + (size_t)kj * S_ + sbase;
    }

    float acc[8] = {0.f,0.f,0.f,0.f,0.f,0.f,0.f,0.f};
    float4 pre[4];
    {
        const float4* g = (const float4*)src;
#pragma unroll
        for (int i = 0; i < 4; ++i) pre[i] = g[i * 256 + t];
    }
    for (int ch = 0; ch < 8; ++ch) {
        __syncthreads();
#pragma unroll
        for (int i = 0; i < 4; ++i) ((float4*)bs)[i * 256 + t] = pre[i];
        __syncthreads();
        if (ch + 1 < 8) {
            const float4* g = (const float4*)(src + (size_t)(ch + 1) * 64 * D_);
#pragma unroll
            for (int i = 0; i < 4; ++i) pre[i] = g[i * 256 + t];
        }
        const int s0 = ch * 64;
#pragma unroll 2
        for (int s4 = 0; s4 < 16; ++s4) {
            float4 w4[8];
#pragma unroll
            for (int j = 0; j < 8; ++j)
                w4[j] = *(const float4*)(Wrow[j] + s0 + s4 * 4);
#pragma unroll
            for (int c = 0; c < 4; ++c) {
                float bval = bs[(s4 * 4 + c) * 64 + lane];
#pragma unroll
                for (int j = 0; j < 8; ++j)
                    acc[j] = fmaf(bval, ((const float*)&w4[j])[c], acc[j]);
            }
        }
    }
#pragma unroll
    for (int j = 0; j < 8; ++j)
        atomicAdd(&outp[(size_t)(k0 + j) * D_ + lane], acc[j]);
}

// ---------------------------------------------------------------------------
// Kernel 2: fused scores -> softmax -> attn write -> out = attn @ Vp.
// Unchanged from R2 (isolate the proj change; counters surface next round).
// ---------------------------------------------------------------------------
__global__ __launch_bounds__(256, 3)
void attn_kernel(const float* __restrict__ Qg, const float* __restrict__ KpT,
                 const float* __restrict__ Vp, float* __restrict__ attn_out,
                 float* __restrict__ outg)
{
    const int st = blockIdx.x;
    const int b  = blockIdx.y;
    const int t  = threadIdx.x;

    __shared__ __align__(16) float smem[12416];
    float* kp_lds = smem;            // phase1: [d 64][k 128] pitch 129 (8256 f)
    float* q_lds  = smem + 8320;     // [s 32][d 64] (2048 f)
    float* at_lds = smem;            // phase3: [s 32][k 256] pitch 260 (8320 f)
    float* vp_lds = smem + 8320;     // phase3: [kk 64][d 64], overlays dead q

    {
        const float4* qg4 = (const float4*)(Qg + ((size_t)b * S_ + (size_t)st * 32) * D_);
#pragma unroll
        for (int i = 0; i < 2; ++i) {
            int f = i * 256 + t;
            ((float4*)q_lds)[f] = qg4[f];
        }
    }

    const int kg = t & 31;
    const int sg = t >> 5;
    const int s0 = sg * 4;

    float acc[4][8];
#pragma unroll
    for (int si = 0; si < 4; ++si)
#pragma unroll
        for (int j = 0; j < 8; ++j) acc[si][j] = 0.f;

    const float4* kpg = (const float4*)(KpT + (size_t)b * KP_ * D_);

    for (int half = 0; half < 2; ++half) {
        __syncthreads();
#pragma unroll
        for (int i = 0; i < 8; ++i) {
            int f  = i * 256 + t;
            int k  = f >> 4;
            int d4 = f & 15;
            float4 v = kpg[(size_t)(half * 128 + k) * 16 + d4];
            kp_lds[(d4 * 4 + 0) * 129 + k] = v.x;
            kp_lds[(d4 * 4 + 1) * 129 + k] = v.y;
            kp_lds[(d4 * 4 + 2) * 129 + k] = v.z;
            kp_lds[(d4 * 4 + 3) * 129 + k] = v.w;
        }
        __syncthreads();
#pragma unroll 2
        for (int d4 = 0; d4 < 16; ++d4) {
            float4 qv[4];
#pragma unroll
            for (int si = 0; si < 4; ++si)
                qv[si] = *(const float4*)&q_lds[(s0 + si) * 64 + d4 * 4];
#pragma unroll
            for (int dd = 0; dd < 4; ++dd) {
                float4 kv = *(const float4*)&kp_lds[(d4 * 4 + dd) * 129 + kg * 4];
#pragma unroll
                for (int si = 0; si < 4; ++si) {
                    float qs = ((const float*)&qv[si])[dd];
                    acc[si][half*4+0] = fmaf(qs, kv.x, acc[si][half*4+0]);
                    acc[si][half*4+1] = fmaf(qs, kv.y, acc[si][half*4+1]);
                    acc[si][half*4+2] = fmaf(qs, kv.z, acc[si][half*4+2]);
                    acc[si][half*4+3] = fmaf(qs, kv.w, acc[si][half*4+3]);
                }
            }
        }
    }

    const float scale = 0.125f;   // 1/sqrt(64)
    float p[4][8];
#pragma unroll
    for (int si = 0; si < 4; ++si) {
        float m = -3.4e38f;
#pragma unroll
        for (int j = 0; j < 8; ++j) {
            p[si][j] = acc[si][j] * scale;
            m = fmaxf(m, p[si][j]);
        }
#pragma unroll
        for (int off = 16; off > 0; off >>= 1)
            m = fmaxf(m, __shfl_xor(m, off, 32));
        float sum = 0.f;
#pragma unroll
        for (int j = 0; j < 8; ++j) {
            p[si][j] = __expf(p[si][j] - m);
            sum += p[si][j];
        }
#pragma unroll
        for (int off = 16; off > 0; off >>= 1)
            sum += __shfl_xor(sum, off, 32);
        float inv = 1.f / sum;
#pragma unroll
        for (int j = 0; j < 8; ++j) p[si][j] *= inv;
    }

    __syncthreads();

    float* attn_b = attn_out + ((size_t)b * S_ + (size_t)st * 32) * KP_;
#pragma unroll
    for (int si = 0; si < 4; ++si) {
        int srow = s0 + si;
        float4 pa = make_float4(p[si][0], p[si][1], p[si][2], p[si][3]);
        float4 pb = make_float4(p[si][4], p[si][5], p[si][6], p[si][7]);
        *(float4*)&attn_b[(size_t)srow * KP_ + kg * 4]       = pa;
        *(float4*)&attn_b[(size_t)srow * KP_ + 128 + kg * 4] = pb;
        *(float4*)&at_lds[srow * 260 + kg * 4]       = pa;
        *(float4*)&at_lds[srow * 260 + 128 + kg * 4] = pb;
    }

    const int dg  = t & 15;
    const int d0  = dg * 4;
    const int sg3 = t >> 4;
    const int sA  = sg3 * 2, sB = sA + 1;
    float accA[4] = {0,0,0,0}, accB[4] = {0,0,0,0};

    const float4* vg4 = (const float4*)(Vp + (size_t)b * KP_ * D_);
    for (int kc = 0; kc < 4; ++kc) {
        __syncthreads();
#pragma unroll
        for (int i = 0; i < 4; ++i) {
            int f = i * 256 + t;
            ((float4*)vp_lds)[f] = vg4[kc * 1024 + f];
        }
        __syncthreads();
#pragma unroll 4
        for (int kk = 0; kk < 64; ++kk) {
            int k = kc * 64 + kk;
            float4 v4 = *(const float4*)&vp_lds[kk * 64 + d0];
            float a0 = at_lds[sA * 260 + k];
            float a1 = at_lds[sB * 260 + k];
            accA[0] = fmaf(a0, v4.x, accA[0]);
            accA[1] = fmaf(a0, v4.y, accA[1]);
            accA[2] = fmaf(a0, v4.z, accA[2]);
            accA[3] = fmaf(a0, v4.w, accA[3]);
            accB[0] = fmaf(a1, v4.x, accB[0]);
            accB[1] = fmaf(a1, v4.y, accB[1]);
            accB[2] = fmaf(a1, v4.z, accB[2]);
            accB[3] = fmaf(a1, v4.w, accB[3]);
        }
    }

    float* out_b = outg + ((size_t)b * S_ + (size_t)st * 32) * D_;
    *(float4*)&out_b[(size_t)sA * D_ + d0] = make_float4(accA[0], accA[1], accA[2], accA[3]);
    *(float4*)&out_b[(size_t)sB * D_ + d0] = make_float4(accB[0], accB[1], accB[2], accB[3]);
}

extern "C" void kernel_launch(void* const* d_in, const int* in_sizes, int n_in,
                              void* d_out, int out_size, void* d_ws, size_t ws_size,
                              hipStream_t stream) {
    const float* Q   = (const float*)d_in[0];
    const float* K   = (const float*)d_in[1];
    const float* V   = (const float*)d_in[2];
    const float* E_w = (const float*)d_in[3];
    const float* E_b = (const float*)d_in[4];
    const float* F_w = (const float*)d_in[5];
    const float* F_b = (const float*)d_in[6];

    float* out  = (float*)d_out;                       // [B,S,D]
    float* attn = out + (size_t)B_ * S_ * D_;          // [B,S,KP]

    float* KpT   = (float*)d_ws;                       // [B,KP,D]   1 MB
    float* Vp    = KpT + NELEM;                        // [B,KP,D]   1 MB
    float* Ppart = Vp + NELEM;                         // [2*NSC][B,KP,D] 16 MB

    const size_t need = (size_t)(2 + 2 * NSC) * NELEM * sizeof(float);

    if (ws_size >= need) {
        proj_partial_kernel<<<dim3(KP_ / 32, 2, B_ * NSC), 256, 0, stream>>>(
            K, V, E_w, F_w, Ppart);
        reduce_kernel<<<dim3(NELEM / 4 / 256), 256, 0, stream>>>(
            (const float4*)Ppart, E_b, F_b, (float4*)KpT, (float4*)Vp);
    } else {
        init_bias_kernel<<<dim3(NELEM / 256), 256, 0, stream>>>(E_b, F_b, KpT, Vp);
        proj_atomic_kernel<<<dim3(KP_ / 32, 2, B_ * NSC), 256, 0, stream>>>(
            K, V, E_w, F_w, KpT, Vp);
    }
    attn_kernel<<<dim3(S_ / 32, B_), 256, 0, stream>>>(Q, KpT, Vp, attn, out);
}

// Round 4
// 213.851 us; speedup vs baseline: 2.7509x; 1.9518x over previous
//
#include <hip/hip_runtime.h>

// Linformer head, MFMA bf16-split rewrite. B=16, S=4096, D=64, KP=256.
// d_in: Q, K, V [B,S,D] f32; E_w,F_w [KP,S] f32; E_b,F_b [KP] f32
// d_out: out[B,S,D] ++ attn[B,S,KP] f32
// Stages: wcvt (W->bf16 hi/lo planes) -> proj (split-bf16 MFMA, partials in the
// attn out-region which is dead until the last kernel) -> reduce (+bias ->
// Kp hi/lo k-major, Vp hi d-major bf16 planes) -> attn (scores MFMA 3-term ->
// softmax in C-layout regs -> P LDS round-trip -> PV MFMA).
// ws: Whi 4MB | Wlo 4MB | Kp_hi .5 | Kp_lo .5 | Vp_hi .5  = 9.5 MB (< 18.9 proven).

#define B_  16
#define S_  4096
#define D_  64
#define KP_ 256

typedef short v8s __attribute__((ext_vector_type(8)));
typedef float v4f __attribute__((ext_vector_type(4)));

__device__ __forceinline__ short f2bf(float x) {        // RNE f32 -> bf16
    union { float f; unsigned u; } v; v.f = x;
    unsigned r = v.u + 0x7FFFu + ((v.u >> 16) & 1u);
    return (short)(r >> 16);
}
__device__ __forceinline__ float bf2f(short h) {
    union { float f; unsigned u; } v; v.u = ((unsigned)(unsigned short)h) << 16;
    return v.f;
}

// ---------------------------------------------------------------------------
// Kernel 1: W fp32 -> bf16 hi/lo planes. grid (1024, 2) x 256.
// ---------------------------------------------------------------------------
__global__ __launch_bounds__(256)
void wcvt_kernel(const float* __restrict__ E_w, const float* __restrict__ F_w,
                 short* __restrict__ Whi, short* __restrict__ Wlo)
{
    const int p = blockIdx.y;
    const float* W = p ? F_w : E_w;
    const size_t i4 = (size_t)blockIdx.x * 256 + threadIdx.x;   // float4 idx
    float4 v = ((const float4*)W)[i4];
    short4 h, lo;
    h.x = f2bf(v.x); lo.x = f2bf(v.x - bf2f(h.x));
    h.y = f2bf(v.y); lo.y = f2bf(v.y - bf2f(h.y));
    h.z = f2bf(v.z); lo.z = f2bf(v.z - bf2f(h.z));
    h.w = f2bf(v.w); lo.w = f2bf(v.w - bf2f(h.w));
    const size_t o = (size_t)p * (KP_ * S_) + i4 * 4;
    *(short4*)(Whi + o) = h;
    *(short4*)(Wlo + o) = lo;
}

// ---------------------------------------------------------------------------
// Kernel 2: projections via MFMA, split-S partials.
// grid (sc 8, p 2, b 16) x 512 thr (8 waves). 1 block/CU, 2 waves/SIMD.
// p=0: PpartK[sc][b][k 256][d 64] += E_w-chunk @ K-chunk   (C[k,d]: A=W, B=src)
// p=1: PpartV[sc][b][d 64][k 256] += (F_w-chunk @ V-chunk)^T (C'[d,k]: A=src, B=W)
// src staged per 32-s step into MFMA-fragment-order LDS (hi/lo), dbl-buffered.
// W fragments read straight from bf16 planes (16B contiguous per lane).
// ---------------------------------------------------------------------------
__global__ __launch_bounds__(512, 2)
void proj_mfma_kernel(const float* __restrict__ Kg, const float* __restrict__ Vg,
                      const short* __restrict__ Whi, const short* __restrict__ Wlo,
                      float* __restrict__ PpartK, float* __restrict__ PpartV)
{
    const int sc = blockIdx.x;     // s-chunk of 512
    const int p  = blockIdx.y;     // 0 -> Kp, 1 -> Vp
    const int b  = blockIdx.z;

    const float* src = (p ? Vg : Kg) + ((size_t)b * S_ + sc * 512) * D_;
    const short* Wh = Whi + (size_t)p * KP_ * S_ + sc * 512;
    const short* Wl = Wlo + (size_t)p * KP_ * S_ + sc * 512;

    __shared__ __align__(16) short Af[2][2][4][512];  // [buf][plane][mt=d/16][fraglane*8] 16KB

    const int t  = threadIdx.x;
    const int wv = t >> 6;
    const int l  = t & 63;

    v4f acc[2][4];
#pragma unroll
    for (int i = 0; i < 2; ++i)
#pragma unroll
        for (int m = 0; m < 4; ++m) acc[i][m] = (v4f){0.f, 0.f, 0.f, 0.f};

    // staging role (threads 0..255): thread owns (d = sd, s-oct = soct) -> one frag-lane
    const bool do_stage = (t < 256);
    const int sd   = t & 63;
    const int soct = (t >> 6) & 3;
    const int smt  = sd >> 4;
    const int sfl  = (sd & 15) + soct * 16;

    float g[8];
    if (do_stage) {
        const float* sp = src + (size_t)(soct * 8) * D_ + sd;
#pragma unroll
        for (int j = 0; j < 8; ++j) g[j] = sp[(size_t)j * D_];
        v8s hi, lo;
#pragma unroll
        for (int j = 0; j < 8; ++j) { short h = f2bf(g[j]); hi[j] = h; lo[j] = f2bf(g[j] - bf2f(h)); }
        *(v8s*)&Af[0][0][smt][sfl * 8] = hi;
        *(v8s*)&Af[0][1][smt][sfl * 8] = lo;
    }
    __syncthreads();

    const int krow0 = wv * 32;   // wave's 32-wide k range

    for (int st = 0; st < 16; ++st) {
        const int cur = st & 1;
        if (st + 1 < 16 && do_stage) {      // issue next-step loads (waited at cvt below)
            const float* sp = src + (size_t)((st + 1) * 32 + soct * 8) * D_ + sd;
#pragma unroll
            for (int j = 0; j < 8; ++j) g[j] = sp[(size_t)j * D_];
        }
        // W fragments (global bf16 planes, contiguous 16B per lane)
        v8s wh[2], wl2[2];
#pragma unroll
        for (int i = 0; i < 2; ++i) {
            size_t off = (size_t)(krow0 + i * 16 + (l & 15)) * S_ + st * 32 + (l >> 4) * 8;
            wh[i]  = *(const v8s*)(Wh + off);
            wl2[i] = *(const v8s*)(Wl + off);
        }
        // src fragments (LDS, fragment order: lane reads its own 16B)
        v8s sh[4], sl[4];
#pragma unroll
        for (int m = 0; m < 4; ++m) {
            sh[m] = *(const v8s*)&Af[cur][0][m][l * 8];
            sl[m] = *(const v8s*)&Af[cur][1][m][l * 8];
        }
        if (p == 0) {       // C[k,d] = W @ src : A=W, B=src
#pragma unroll
            for (int i = 0; i < 2; ++i)
#pragma unroll
                for (int m = 0; m < 4; ++m) {
                    acc[i][m] = __builtin_amdgcn_mfma_f32_16x16x32_bf16(wh[i],  sh[m], acc[i][m], 0, 0, 0);
                    acc[i][m] = __builtin_amdgcn_mfma_f32_16x16x32_bf16(wh[i],  sl[m], acc[i][m], 0, 0, 0);
                    acc[i][m] = __builtin_amdgcn_mfma_f32_16x16x32_bf16(wl2[i], sh[m], acc[i][m], 0, 0, 0);
                }
        } else {            // C'[d,k] = src^T @ W^T : A=src, B=W
#pragma unroll
            for (int i = 0; i < 2; ++i)
#pragma unroll
                for (int m = 0; m < 4; ++m) {
                    acc[i][m] = __builtin_amdgcn_mfma_f32_16x16x32_bf16(sh[m], wh[i],  acc[i][m], 0, 0, 0);
                    acc[i][m] = __builtin_amdgcn_mfma_f32_16x16x32_bf16(sl[m], wh[i],  acc[i][m], 0, 0, 0);
                    acc[i][m] = __builtin_amdgcn_mfma_f32_16x16x32_bf16(sh[m], wl2[i], acc[i][m], 0, 0, 0);
                }
        }
        if (st + 1 < 16 && do_stage) {      // convert + write next buffer
            v8s hi, lo;
#pragma unroll
            for (int j = 0; j < 8; ++j) { short h = f2bf(g[j]); hi[j] = h; lo[j] = f2bf(g[j] - bf2f(h)); }
            *(v8s*)&Af[cur ^ 1][0][smt][sfl * 8] = hi;
            *(v8s*)&Af[cur ^ 1][1][smt][sfl * 8] = lo;
        }
        __syncthreads();
    }

    if (p == 0) {
        float* outp = PpartK + ((size_t)sc * B_ + b) * (KP_ * D_);
#pragma unroll
        for (int i = 0; i < 2; ++i)
#pragma unroll
            for (int m = 0; m < 4; ++m)
#pragma unroll
                for (int r = 0; r < 4; ++r) {
                    int k = krow0 + i * 16 + (l >> 4) * 4 + r;
                    int d = m * 16 + (l & 15);
                    outp[(size_t)k * D_ + d] = acc[i][m][r];
                }
    } else {
        float* outp = PpartV + ((size_t)sc * B_ + b) * (KP_ * D_);
#pragma unroll
        for (int i = 0; i < 2; ++i)
#pragma unroll
            for (int m = 0; m < 4; ++m)
#pragma unroll
                for (int r = 0; r < 4; ++r) {
                    int d = m * 16 + (l >> 4) * 4 + r;
                    int k = krow0 + i * 16 + (l & 15);
                    outp[(size_t)d * KP_ + k] = acc[i][m][r];
                }
    }
}

// ---------------------------------------------------------------------------
// Kernel 3: reduce partials + bias -> bf16 planes.
// Kp (k-major [b][k][d]) -> hi+lo; Vp (d-major [b][d][k]) -> hi. grid 512x256.
// ---------------------------------------------------------------------------
__global__ __launch_bounds__(256)
void reduce_kernel(const float* __restrict__ PpartK, const float* __restrict__ PpartV,
                   const float* __restrict__ E_b, const float* __restrict__ F_b,
                   short* __restrict__ Kp_hi, short* __restrict__ Kp_lo,
                   short* __restrict__ Vp_hi)
{
    const int j    = blockIdx.x * 256 + threadIdx.x;   // 0..131071
    const int side = j >> 16;                          // block-uniform
    const int i4   = j & 65535;
    const int flat = i4 * 4;                           // b*16384 + dk
    const int b    = flat >> 14;
    const int dk   = flat & 16383;

    if (side == 0) {
        float4 a = make_float4(0.f, 0.f, 0.f, 0.f);
#pragma unroll
        for (int sc = 0; sc < 8; ++sc) {
            float4 v = *(const float4*)(PpartK + ((size_t)sc * B_ + b) * (KP_ * D_) + dk);
            a.x += v.x; a.y += v.y; a.z += v.z; a.w += v.w;
        }
        float be = E_b[dk >> 6];                       // k = dk/64 (d contiguous)
        a.x += be; a.y += be; a.z += be; a.w += be;
        short4 h, lo;
        h.x = f2bf(a.x); lo.x = f2bf(a.x - bf2f(h.x));
        h.y = f2bf(a.y); lo.y = f2bf(a.y - bf2f(h.y));
        h.z = f2bf(a.z); lo.z = f2bf(a.z - bf2f(h.z));
        h.w = f2bf(a.w); lo.w = f2bf(a.w - bf2f(h.w));
        *(short4*)(Kp_hi + (size_t)b * 16384 + dk) = h;
        *(short4*)(Kp_lo + (size_t)b * 16384 + dk) = lo;
    } else {
        float4 a = make_float4(0.f, 0.f, 0.f, 0.f);
#pragma unroll
        for (int sc = 0; sc < 8; ++sc) {
            float4 v = *(const float4*)(PpartV + ((size_t)sc * B_ + b) * (KP_ * D_) + dk);
            a.x += v.x; a.y += v.y; a.z += v.z; a.w += v.w;
        }
        float4 bf = *(const float4*)(F_b + (dk & 255));   // k contiguous
        a.x += bf.x; a.y += bf.y; a.z += bf.z; a.w += bf.w;
        short4 h;
        h.x = f2bf(a.x); h.y = f2bf(a.y); h.z = f2bf(a.z); h.w = f2bf(a.w);
        *(short4*)(Vp_hi + (size_t)b * 16384 + dk) = h;
    }
}

// ---------------------------------------------------------------------------
// Kernel 4: scores -> softmax -> attn write -> out, all MFMA.
// grid (64 st, 16 b) x 256 thr (4 waves); wave owns 16 s-rows.
// LDS: Q frags 16KB + P (s-major, pitch 264 bf16) 33KB -> 3 blocks/CU.
// ---------------------------------------------------------------------------
__global__ __launch_bounds__(256, 3)
void attn_mfma_kernel(const float* __restrict__ Qg,
                      const short* __restrict__ Kp_hi, const short* __restrict__ Kp_lo,
                      const short* __restrict__ Vp_hi,
                      float* __restrict__ attn_out, float* __restrict__ outg)
{
    const int st = blockIdx.x;
    const int b  = blockIdx.y;
    const int t  = threadIdx.x;
    const int wv = t >> 6;
    const int l  = t & 63;

    __shared__ __align__(16) short Qf[2][2][4][512];   // [kd][plane][mt=s/16][fraglane*8]
    __shared__ __align__(16) short Pl[64 * 264];       // attn tile, pitch 264

    {   // stage Q fragments (hi/lo)
        const int s    = t & 63;
        const int doct = t >> 6;
        const float* qrow = Qg + ((size_t)b * S_ + st * 64 + s) * D_;
        const int mt = s >> 4, fl = (s & 15) + doct * 16;
#pragma unroll
        for (int kd = 0; kd < 2; ++kd) {
            float4 v0 = *(const float4*)(qrow + kd * 32 + doct * 8);
            float4 v1 = *(const float4*)(qrow + kd * 32 + doct * 8 + 4);
            float gq[8] = {v0.x, v0.y, v0.z, v0.w, v1.x, v1.y, v1.z, v1.w};
            v8s hi, lo;
#pragma unroll
            for (int jj = 0; jj < 8; ++jj) { short h = f2bf(gq[jj]); hi[jj] = h; lo[jj] = f2bf(gq[jj] - bf2f(h)); }
            *(v8s*)&Qf[kd][0][mt][fl * 8] = hi;
            *(v8s*)&Qf[kd][1][mt][fl * 8] = lo;
        }
    }
    __syncthreads();

    // scores: C2[16 s x 256 k], 3-term split
    v4f acc2[16];
#pragma unroll
    for (int nt = 0; nt < 16; ++nt) acc2[nt] = (v4f){0.f, 0.f, 0.f, 0.f};
    const size_t kb = (size_t)b * (KP_ * D_);
#pragma unroll
    for (int kd = 0; kd < 2; ++kd) {
        v8s Ah = *(const v8s*)&Qf[kd][0][wv][l * 8];
        v8s Al = *(const v8s*)&Qf[kd][1][wv][l * 8];
#pragma unroll
        for (int nt = 0; nt < 16; ++nt) {
            size_t off = kb + (size_t)(nt * 16 + (l & 15)) * D_ + kd * 32 + (l >> 4) * 8;
            v8s Bh = *(const v8s*)(Kp_hi + off);
            v8s Bl = *(const v8s*)(Kp_lo + off);
            acc2[nt] = __builtin_amdgcn_mfma_f32_16x16x32_bf16(Ah, Bh, acc2[nt], 0, 0, 0);
            acc2[nt] = __builtin_amdgcn_mfma_f32_16x16x32_bf16(Al, Bh, acc2[nt], 0, 0, 0);
            acc2[nt] = __builtin_amdgcn_mfma_f32_16x16x32_bf16(Ah, Bl, acc2[nt], 0, 0, 0);
        }
    }

    // softmax per row (C layout: row = wv*16 + (l>>4)*4 + r, col = nt*16 + (l&15))
    const float scale = 0.125f;   // 1/sqrt(64)
    float* attn_b = attn_out + ((size_t)b * S_ + st * 64) * KP_;
#pragma unroll
    for (int r = 0; r < 4; ++r) {
        float m = -3.4e38f;
#pragma unroll
        for (int nt = 0; nt < 16; ++nt) m = fmaxf(m, acc2[nt][r]);
        m = fmaxf(m, __shfl_xor(m, 1));
        m = fmaxf(m, __shfl_xor(m, 2));
        m = fmaxf(m, __shfl_xor(m, 4));
        m = fmaxf(m, __shfl_xor(m, 8));
        float sum = 0.f;
#pragma unroll
        for (int nt = 0; nt < 16; ++nt) {
            float e = __expf((acc2[nt][r] - m) * scale);
            acc2[nt][r] = e; sum += e;
        }
        sum += __shfl_xor(sum, 1);
        sum += __shfl_xor(sum, 2);
        sum += __shfl_xor(sum, 4);
        sum += __shfl_xor(sum, 8);
        const float inv = 1.f / sum;
        const int s_loc = wv * 16 + (l >> 4) * 4 + r;
#pragma unroll
        for (int nt = 0; nt < 16; ++nt) {
            float pv = acc2[nt][r] * inv;
            attn_b[(size_t)s_loc * KP_ + nt * 16 + (l & 15)] = pv;
            Pl[s_loc * 264 + nt * 16 + (l & 15)] = f2bf(pv);
        }
    }
    // PV: rows wv*16..+16 were written by this wave only -> no barrier needed
    v4f acc3[4];
#pragma unroll
    for (int nt = 0; nt < 4; ++nt) acc3[nt] = (v4f){0.f, 0.f, 0.f, 0.f};
#pragma unroll
    for (int kc = 0; kc < 8; ++kc) {
        v8s A3 = *(const v8s*)&Pl[(wv * 16 + (l & 15)) * 264 + kc * 32 + (l >> 4) * 8];
#pragma unroll
        for (int nt = 0; nt < 4; ++nt) {
            size_t off = kb + (size_t)(nt * 16 + (l & 15)) * KP_ + kc * 32 + (l >> 4) * 8;
            v8s B3 = *(const v8s*)(Vp_hi + off);
            acc3[nt] = __builtin_amdgcn_mfma_f32_16x16x32_bf16(A3, B3, acc3[nt], 0, 0, 0);
        }
    }
    float* out_b = outg + ((size_t)b * S_ + st * 64) * D_;
#pragma unroll
    for (int nt = 0; nt < 4; ++nt)
#pragma unroll
        for (int r = 0; r < 4; ++r) {
            int s_loc = wv * 16 + (l >> 4) * 4 + r;
            out_b[(size_t)s_loc * D_ + nt * 16 + (l & 15)] = acc3[nt][r];
        }
}

extern "C" void kernel_launch(void* const* d_in, const int* in_sizes, int n_in,
                              void* d_out, int out_size, void* d_ws, size_t ws_size,
                              hipStream_t stream) {
    const float* Q   = (const float*)d_in[0];
    const float* K   = (const float*)d_in[1];
    const float* V   = (const float*)d_in[2];
    const float* E_w = (const float*)d_in[3];
    const float* E_b = (const float*)d_in[4];
    const float* F_w = (const float*)d_in[5];
    const float* F_b = (const float*)d_in[6];

    float* out  = (float*)d_out;                        // [B,S,D]
    float* attn = out + (size_t)B_ * S_ * D_;           // [B,S,KP]

    // ws: bf16 planes (9.5 MB total)
    short* Whi   = (short*)d_ws;                        // [2][KP][S]  4 MB
    short* Wlo   = Whi + (size_t)2 * KP_ * S_;          // 4 MB
    short* Kp_hi = Wlo + (size_t)2 * KP_ * S_;          // [B][KP][D] k-major, 512 KB
    short* Kp_lo = Kp_hi + (size_t)B_ * KP_ * D_;
    short* Vp_hi = Kp_lo + (size_t)B_ * KP_ * D_;       // [B][D][KP] d-major

    // partials live in the attn output region (dead until attn_mfma_kernel)
    float* PpartK = attn;                               // [8][B][KP*D]  8 MB
    float* PpartV = attn + (size_t)8 * B_ * KP_ * D_;   // [8][B][KP*D]  8 MB

    wcvt_kernel<<<dim3(KP_ * S_ / 4 / 256, 2), 256, 0, stream>>>(E_w, F_w, Whi, Wlo);
    proj_mfma_kernel<<<dim3(8, 2, B_), 512, 0, stream>>>(K, V, Whi, Wlo, PpartK, PpartV);
    reduce_kernel<<<dim3(512), 256, 0, stream>>>(PpartK, PpartV, E_b, F_b, Kp_hi, Kp_lo, Vp_hi);
    attn_mfma_kernel<<<dim3(S_ / 64, B_), 256, 0, stream>>>(Q, Kp_hi, Kp_lo, Vp_hi, attn, out);
}